// Round 5
// baseline (588.825 us; speedup 1.0000x reference)
//
#include <hip/hip_runtime.h>
#include <hip/hip_bf16.h>
#include <stdint.h>

#define NN     30000
#define MPAD   30080          // 470 * 64
#define RR     8
#define NBASES 30
#define KD     256
#define EE     480000
#define NSEG   (NN * RR)
#define KTOT   2304           // 8 rels x 256 + 256 root
#define ELDS   1024           // staged edge-chunk cap (block/rel avg ~128)

typedef unsigned short u16;
typedef __attribute__((ext_vector_type(8))) short bf16x8;   // 8 bf16 = 4 VGPRs
typedef __attribute__((ext_vector_type(4))) float f32x4;

__device__ __forceinline__ u16 f2b(float f) {
  union { float f; uint32_t u; } v; v.f = f;
  return (u16)((v.u + 0x7fffu + ((v.u >> 16) & 1u)) >> 16);   // RNE
}
__device__ __forceinline__ float b2f(u16 h) {
  union { uint32_t u; float f; } v; v.u = ((uint32_t)h) << 16;
  return v.f;
}

// ------- fused per-(d,r) mean + GEMM ---------------------------------------
// Block: 64 dst rows x full N (256 or 128), 256 threads = 4 waves.
// Phases r=0..7: gather-mean rel r's edges into Mlds (64x256 bf16, stride 264),
// then MFMA over K-span [r*256, r*256+256) vs BT (global, L2-hot).
// Phase r=8: self term, A-frags straight from X rows (K-span [2048,2304)).
// LAST=false: +bias, leaky, bf16 -> ob [MPAD x 256]
// LAST=true : +bias -> of [NN x 128] f32
template<bool LAST>
__global__ __launch_bounds__(256, 2)
void k_fused(const u16* __restrict__ X, const int* __restrict__ off3,
             const int* __restrict__ esrc, const u16* __restrict__ BT,
             const float* __restrict__ bias,
             u16* __restrict__ ob, float* __restrict__ of) {
  constexpr int MI = LAST ? 2 : 4;
  __shared__ u16 Mlds[64 * 264];     // +8 u16 pad per row -> 2-way banks on av reads
  __shared__ int Elds[ELDS];
  const int tid = threadIdx.x;
  const int w = tid >> 6, lane = tid & 63;
  const int bm = blockIdx.x * 64;
  const int l15 = lane & 15, l4 = lane >> 4;
  const int wm = LAST ? ((w >> 1) * 32) : 0;
  const int wn = LAST ? ((w & 1) * 64) : (w * 64);

  f32x4 zero4 = {0.f, 0.f, 0.f, 0.f};
  f32x4 acc[MI][4];
  #pragma unroll
  for (int mi = 0; mi < MI; ++mi)
    #pragma unroll
    for (int ni = 0; ni < 4; ++ni) acc[mi][ni] = zero4;

  #pragma unroll 1
  for (int r = 0; r < 9; ++r) {
    if (r < 8) {
      __syncthreads();                       // Mlds/Elds reuse vs prev phase
      // ---- stage this (block, rel)'s contiguous edge chunk into LDS ----
      int cb0 = 0, chunk = 0;
      if (bm < NN) {
        int hi = (bm + 64 < NN) ? bm + 64 : NN;
        cb0 = off3[r * NN + bm];
        chunk = off3[r * NN + hi] - cb0;
      }
      int lim = chunk < ELDS ? chunk : ELDS;
      for (int i = tid; i < lim; i += 256) Elds[i] = esrc[cb0 + i];
      __syncthreads();
      // ---- per-node mean: wave w handles nodes w*16 .. w*16+15 ----
      #pragma unroll 1
      for (int it = 0; it < 16; ++it) {
        int dl = w * 16 + it;
        int d = bm + dl;
        int e0r = 0, e1r = 0;
        if (d < NN) {
          e0r = off3[r * NN + d] - cb0;
          e1r = off3[r * NN + d + 1] - cb0;
        }
        float a0 = 0.f, a1 = 0.f, a2 = 0.f, a3 = 0.f;
        #pragma unroll 1
        for (int e = e0r; e < e1r; e += 4) {
          int idx[4]; int sv[4]; uint2 pk[4];
          #pragma unroll
          for (int j = 0; j < 4; ++j) {
            int ee = e + j;
            idx[j] = (ee < e1r) ? ee : e0r;
          }
          #pragma unroll
          for (int j = 0; j < 4; ++j)
            sv[j] = (idx[j] < ELDS) ? Elds[idx[j]] : esrc[cb0 + idx[j]];
          #pragma unroll
          for (int j = 0; j < 4; ++j)
            pk[j] = *(const uint2*)&X[(size_t)sv[j] * KD + lane * 4];
          #pragma unroll
          for (int j = 0; j < 4; ++j) {
            if (e + j < e1r) {
              a0 += b2f((u16)pk[j].x); a1 += b2f((u16)(pk[j].x >> 16));
              a2 += b2f((u16)pk[j].y); a3 += b2f((u16)(pk[j].y >> 16));
            }
          }
        }
        float sc = (e1r > e0r) ? 1.f / (float)(e1r - e0r) : 0.f;
        uint2 o;
        o.x = ((uint32_t)f2b(a1 * sc) << 16) | (uint32_t)f2b(a0 * sc);
        o.y = ((uint32_t)f2b(a3 * sc) << 16) | (uint32_t)f2b(a2 * sc);
        *(uint2*)&Mlds[dl * 264 + lane * 4] = o;   // lane covers ch 4*lane..+4
      }
      __syncthreads();
    }
    // ---- MFMA over this phase's K-span ----
    const int kbase = r * 256;                     // r==8 -> 2048 (self/root)
    if (r < 8) {
      #pragma unroll
      for (int kc = 0; kc < 8; ++kc) {
        bf16x8 av[MI], bv[4];
        #pragma unroll
        for (int mi = 0; mi < MI; ++mi)
          av[mi] = *(const bf16x8*)&Mlds[(wm + mi * 16 + l15) * 264 + kc * 32 + l4 * 8];
        #pragma unroll
        for (int ni = 0; ni < 4; ++ni)
          bv[ni] = *(const bf16x8*)&BT[(size_t)(wn + ni * 16 + l15) * KTOT + kbase + kc * 32 + l4 * 8];
        #pragma unroll
        for (int mi = 0; mi < MI; ++mi)
          #pragma unroll
          for (int ni = 0; ni < 4; ++ni)
            acc[mi][ni] = __builtin_amdgcn_mfma_f32_16x16x32_bf16(av[mi], bv[ni], acc[mi][ni], 0, 0, 0);
      }
    } else {
      #pragma unroll
      for (int kc = 0; kc < 8; ++kc) {
        bf16x8 av[MI], bv[4];
        #pragma unroll
        for (int mi = 0; mi < MI; ++mi)
          av[mi] = *(const bf16x8*)&X[(size_t)(bm + wm + mi * 16 + l15) * KD + kc * 32 + l4 * 8];
        #pragma unroll
        for (int ni = 0; ni < 4; ++ni)
          bv[ni] = *(const bf16x8*)&BT[(size_t)(wn + ni * 16 + l15) * KTOT + kbase + kc * 32 + l4 * 8];
        #pragma unroll
        for (int mi = 0; mi < MI; ++mi)
          #pragma unroll
          for (int ni = 0; ni < 4; ++ni)
            acc[mi][ni] = __builtin_amdgcn_mfma_f32_16x16x32_bf16(av[mi], bv[ni], acc[mi][ni], 0, 0, 0);
      }
    }
  }

  // ---- epilogue: C/D layout col=lane&15, row=(lane>>4)*4+reg ----
  #pragma unroll
  for (int mi = 0; mi < MI; ++mi) {
    #pragma unroll
    for (int ni = 0; ni < 4; ++ni) {
      int col = wn + ni * 16 + l15;
      float bb = bias[col];
      #pragma unroll
      for (int v = 0; v < 4; ++v) {
        int row = bm + wm + mi * 16 + l4 * 4 + v;
        float val = acc[mi][ni][v] + bb;
        if (!LAST) {
          val = val > 0.f ? val : 0.01f * val;
          ob[(size_t)row * KD + col] = f2b(val);   // rows >= NN: finite, masked later
        } else if (row < NN) {
          of[(size_t)row * 128 + col] = val;
        }
      }
    }
  }
}

// ------- small kernels ------------------------------------------------------
__global__ void k_cast_x(const float* __restrict__ x, u16* __restrict__ xb) {
  int t = blockIdx.x * 256 + threadIdx.x;
  if (t < NN * KD / 4) {
    float4 v = ((const float4*)x)[t];
    union { u16 h[4]; uint2 u; } p;
    p.h[0] = f2b(v.x); p.h[1] = f2b(v.y); p.h[2] = f2b(v.z); p.h[3] = f2b(v.w);
    ((uint2*)xb)[t] = p.u;
  }
}

// BT1[o, k] k<2048: sum_b comp1[r,b]*bases1[b,i,o]; k in [2048,2304): root1[i,o]
__global__ void k_combine1(const float* __restrict__ bases, const float* __restrict__ comp,
                           const float* __restrict__ root, u16* __restrict__ BT) {
  int k = blockIdx.x, o = threadIdx.x;   // 2304 blocks x 256 threads
  float v;
  if (k < 2048) {
    int r = k >> 8, i = k & 255;
    float acc = 0.f;
    #pragma unroll
    for (int b = 0; b < NBASES; ++b)
      acc += comp[r * NBASES + b] * bases[(size_t)b * 65536 + i * 256 + o];
    v = acc;
  } else {
    v = root[(k - 2048) * 256 + o];
  }
  BT[(size_t)o * KTOT + k] = f2b(v);
}

__global__ void k_combine2(const float* __restrict__ bases, const float* __restrict__ comp,
                           const float* __restrict__ root, u16* __restrict__ BT) {
  int k = blockIdx.x, o = threadIdx.x;   // 2304 blocks x 128 threads
  float v;
  if (k < 2048) {
    int r = k >> 8, i = k & 255;
    float acc = 0.f;
    #pragma unroll
    for (int b = 0; b < NBASES; ++b)
      acc += comp[r * NBASES + b] * bases[(size_t)b * 32768 + i * 128 + o];
    v = acc;
  } else {
    v = root[(k - 2048) * 128 + o];
  }
  BT[(size_t)o * KTOT + k] = f2b(v);
}

// histogram over key = rel*NN + dst
__global__ void k_hist(const int* __restrict__ ei, const int* __restrict__ ety,
                       int* __restrict__ cnt) {
  int e = blockIdx.x * 256 + threadIdx.x;
  if (e < EE) atomicAdd(&cnt[ety[e] * NN + ei[EE + e]], 1);
}

// hierarchical exclusive scan of cnt[NSEG] -> off3
__global__ void k_scan1(const int* __restrict__ cnt, int* __restrict__ off3,
                        int* __restrict__ bsum) {
  __shared__ int lds[1024];
  int i = blockIdx.x * 1024 + threadIdx.x;
  int v = (i < NSEG) ? cnt[i] : 0;
  lds[threadIdx.x] = v;
  __syncthreads();
  #pragma unroll
  for (int s = 1; s < 1024; s <<= 1) {
    int u = (threadIdx.x >= (unsigned)s) ? lds[threadIdx.x - s] : 0;
    __syncthreads();
    lds[threadIdx.x] += u;
    __syncthreads();
  }
  if (i < NSEG) off3[i] = lds[threadIdx.x] - v;
  if (threadIdx.x == 1023) bsum[blockIdx.x] = lds[1023];
}

__global__ void k_scan2(int* __restrict__ bsum, int* __restrict__ boff, int nb) {
  __shared__ int lds[256];
  int v = (threadIdx.x < (unsigned)nb) ? bsum[threadIdx.x] : 0;
  lds[threadIdx.x] = v;
  __syncthreads();
  #pragma unroll
  for (int s = 1; s < 256; s <<= 1) {
    int u = (threadIdx.x >= (unsigned)s) ? lds[threadIdx.x - s] : 0;
    __syncthreads();
    lds[threadIdx.x] += u;
    __syncthreads();
  }
  if (threadIdx.x < (unsigned)nb) boff[threadIdx.x] = lds[threadIdx.x] - v;
}

__global__ void k_scan3(int* __restrict__ off3, const int* __restrict__ boff,
                        int* __restrict__ cursor) {
  int i = blockIdx.x * 1024 + threadIdx.x;
  if (i < NSEG) {
    off3[i] += boff[blockIdx.x];
    cursor[i] = 0;
  }
  if (i == 0) off3[NSEG] = EE;
}

__global__ void k_bucket(const int* __restrict__ ei, const int* __restrict__ ety,
                         const int* __restrict__ off3, int* __restrict__ cursor,
                         int* __restrict__ esrc) {
  int e = blockIdx.x * 256 + threadIdx.x;
  if (e < EE) {
    int seg = ety[e] * NN + ei[EE + e];
    int pos = off3[seg] + atomicAdd(&cursor[seg], 1);
    esrc[pos] = ei[e];
  }
}

// ------- launch -------------------------------------------------------------
extern "C" void kernel_launch(void* const* d_in, const int* in_sizes, int n_in,
                              void* d_out, int out_size, void* d_ws, size_t ws_size,
                              hipStream_t stream) {
  const float* x      = (const float*)d_in[0];
  const int*   ei     = (const int*)d_in[1];
  const int*   ety    = (const int*)d_in[2];
  const float* bases1 = (const float*)d_in[3];
  const float* comp1  = (const float*)d_in[4];
  const float* root1  = (const float*)d_in[5];
  const float* bias1  = (const float*)d_in[6];
  const float* bases2 = (const float*)d_in[7];
  const float* comp2  = (const float*)d_in[8];
  const float* root2  = (const float*)d_in[9];
  const float* bias2  = (const float*)d_in[10];
  float* out = (float*)d_out;

  char* p = (char*)d_ws;
  auto alloc = [&](size_t bytes) {
    char* q = p; p += (bytes + 255) & ~(size_t)255; return q;
  };
  u16* xb     = (u16*)alloc((size_t)MPAD * KD * 2);
  u16* z1b    = (u16*)alloc((size_t)MPAD * KD * 2);
  u16* BT1    = (u16*)alloc((size_t)256 * KTOT * 2);
  u16* BT2    = (u16*)alloc((size_t)128 * KTOT * 2);
  int* cnt    = (int*)alloc((size_t)NSEG * 4);
  int* off3   = (int*)alloc((size_t)(NSEG + 1) * 4);
  int* cursor = (int*)alloc((size_t)NSEG * 4);
  int* esrc   = (int*)alloc((size_t)EE * 4);
  int* bsum   = (int*)alloc((size_t)256 * 4);
  int* boff   = (int*)alloc((size_t)256 * 4);

  const int NB = (NSEG + 1023) / 1024;                 // 235

  // CSR keyed by (rel, dst) -> per (block, rel) edge chunks are contiguous
  hipMemsetAsync(cnt, 0, (size_t)NSEG * 4, stream);
  k_hist<<<(EE + 255) / 256, 256, 0, stream>>>(ei, ety, cnt);
  k_scan1<<<NB, 1024, 0, stream>>>(cnt, off3, bsum);
  k_scan2<<<1, 256, 0, stream>>>(bsum, boff, NB);
  k_scan3<<<NB, 1024, 0, stream>>>(off3, boff, cursor);
  k_bucket<<<(EE + 255) / 256, 256, 0, stream>>>(ei, ety, off3, cursor, esrc);

  // weights + input cast
  k_cast_x<<<NN * KD / 4 / 256, 256, 0, stream>>>(x, xb);
  k_combine1<<<KTOT, 256, 0, stream>>>(bases1, comp1, root1, BT1);
  k_combine2<<<KTOT, 128, 0, stream>>>(bases2, comp2, root2, BT2);

  // fused layers: no H materialization
  k_fused<false><<<MPAD / 64, 256, 0, stream>>>(xb, off3, esrc, BT1, bias1, z1b, nullptr);
  k_fused<true><<<MPAD / 64, 256, 0, stream>>>(z1b, off3, esrc, BT2, bias2, nullptr, out);
}